// Round 1
// baseline (210.029 us; speedup 1.0000x reference)
//
#include <hip/hip_runtime.h>
#include <hip/hip_bf16.h>

// MMD loss. ws layout (floats):
//  [0]   = S1 accumulator (sum of all row norms)
//  [1]   = cross-kernel sum accumulator
//  [2]   = c2 = -log2(e) / (16*bw)
//  [3]   = pad
//  [4..259]    = colsum[256]
//  [260..8451] = sqAll[8192] (row squared-norms, rows 0..4095 = source, 4096..8191 = target)

#define D 256
#define NROWS 4096

__global__ __launch_bounds__(256) void rowstats_kernel(const float* __restrict__ src,
                                                       const float* __restrict__ tgt,
                                                       float* __restrict__ ws) {
  __shared__ float csL[4][256];
  __shared__ float s1L[4];
  int t = threadIdx.x;
  int wave = t >> 6, lane = t & 63;
  int rowBase = blockIdx.x * 64 + wave * 16;
  float cs0 = 0.f, cs1 = 0.f, cs2 = 0.f, cs3 = 0.f, s1 = 0.f;
  for (int r = 0; r < 16; ++r) {
    int row = rowBase + r;
    const float* p = (row < NROWS) ? (src + (size_t)row * D)
                                   : (tgt + (size_t)(row - NROWS) * D);
    float4 v = reinterpret_cast<const float4*>(p)[lane];
    cs0 += v.x; cs1 += v.y; cs2 += v.z; cs3 += v.w;
    float sq = v.x * v.x + v.y * v.y + v.z * v.z + v.w * v.w;
#pragma unroll
    for (int off = 32; off; off >>= 1) sq += __shfl_xor(sq, off, 64);
    if (lane == 0) { ws[260 + row] = sq; s1 += sq; }
  }
  csL[wave][lane * 4 + 0] = cs0;
  csL[wave][lane * 4 + 1] = cs1;
  csL[wave][lane * 4 + 2] = cs2;
  csL[wave][lane * 4 + 3] = cs3;
  if (lane == 0) s1L[wave] = s1;
  __syncthreads();
  float tot = csL[0][t] + csL[1][t] + csL[2][t] + csL[3][t];
  atomicAdd(&ws[4 + t], tot);
  if (t == 0) atomicAdd(&ws[0], s1L[0] + s1L[1] + s1L[2] + s1L[3]);
}

__global__ __launch_bounds__(256) void bw_kernel(float* __restrict__ ws) {
  __shared__ float red[256];
  int t = threadIdx.x;
  float c = ws[4 + t];
  red[t] = c * c;
  __syncthreads();
#pragma unroll
  for (int s = 128; s > 0; s >>= 1) {
    if (t < s) red[t] += red[t + s];
    __syncthreads();
  }
  if (t == 0) {
    double n = 8192.0;
    double sumL2 = 2.0 * n * (double)ws[0] - 2.0 * (double)red[0];
    double bw = sumL2 / (n * n - n) / 4.0;  // KERNEL_MUL^(KERNEL_NUM/2) = 4
    ws[2] = (float)(-1.4426950408889634 / (16.0 * bw));
  }
}

// Cross block: for each (i,j) in [4096]x[4096], d = ||src_i||^2 + ||tgt_j||^2 - 2 src_i.tgt_j,
// accumulate sum over 5 kernel scales via y=exp2(d*c2): y + y^2 + y^4 + y^8 + y^16.
__global__ __launch_bounds__(256) void cross_kernel(const float* __restrict__ A,
                                                    const float* __restrict__ B,
                                                    float* __restrict__ ws) {
  __shared__ float As[64][68];  // [k][m], pad 68 keeps float4 alignment, 2-way bank max
  __shared__ float Bs[64][68];  // [k][n]
  __shared__ float red[256];
  int t = threadIdx.x;
  int bi = blockIdx.x & 63, bj = blockIdx.x >> 6;
  int rowBase = bi * 64, colBase = bj * 64;
  int lr = t >> 4;           // staging row 0..15
  int lc = (t & 15) * 4;     // staging col chunk
  int tx = t & 15, ty = t >> 4;
  float c2 = ws[2];
  float acc[4][4] = {{0.f}};
  for (int k0 = 0; k0 < D; k0 += 64) {
#pragma unroll
    for (int i = 0; i < 4; ++i) {
      int r = lr + i * 16;
      float4 va = *reinterpret_cast<const float4*>(&A[(size_t)(rowBase + r) * D + k0 + lc]);
      As[lc + 0][r] = va.x; As[lc + 1][r] = va.y; As[lc + 2][r] = va.z; As[lc + 3][r] = va.w;
      float4 vb = *reinterpret_cast<const float4*>(&B[(size_t)(colBase + r) * D + k0 + lc]);
      Bs[lc + 0][r] = vb.x; Bs[lc + 1][r] = vb.y; Bs[lc + 2][r] = vb.z; Bs[lc + 3][r] = vb.w;
    }
    __syncthreads();
#pragma unroll 4
    for (int kk = 0; kk < 64; ++kk) {
      float4 a = *reinterpret_cast<const float4*>(&As[kk][ty * 4]);
      float4 b = *reinterpret_cast<const float4*>(&Bs[kk][tx * 4]);
      float av[4] = {a.x, a.y, a.z, a.w};
      float bv[4] = {b.x, b.y, b.z, b.w};
#pragma unroll
      for (int i = 0; i < 4; ++i)
#pragma unroll
        for (int j = 0; j < 4; ++j)
          acc[i][j] = fmaf(av[i], bv[j], acc[i][j]);
    }
    __syncthreads();
  }
  const float* sqA = ws + 260;
  const float* sqB = ws + 260 + NROWS;
  float sA[4], sB[4];
#pragma unroll
  for (int i = 0; i < 4; ++i) {
    sA[i] = sqA[rowBase + ty * 4 + i];
    sB[i] = sqB[colBase + tx * 4 + i];
  }
  float local = 0.f;
#pragma unroll
  for (int i = 0; i < 4; ++i)
#pragma unroll
    for (int j = 0; j < 4; ++j) {
      float dd = sA[i] + sB[j] - 2.0f * acc[i][j];
      float y = __builtin_amdgcn_exp2f(dd * c2);  // exp(-d/(16 bw))
      float y2 = y * y, y4 = y2 * y2, y8 = y4 * y4, y16 = y8 * y8;
      local += y + y2 + y4 + y8 + y16;
    }
  red[t] = local;
  __syncthreads();
#pragma unroll
  for (int s = 128; s > 0; s >>= 1) {
    if (t < s) red[t] += red[t + s];
    __syncthreads();
  }
  if (t == 0) atomicAdd(&ws[1], red[0]);
}

__global__ void finalize_kernel(const float* __restrict__ ws, float* __restrict__ out) {
  // mean over 4096*4096 cross block; loss = -XY - YX = -2*XY
  out[0] = -2.0f * (ws[1] * (1.0f / 16777216.0f));
}

extern "C" void kernel_launch(void* const* d_in, const int* in_sizes, int n_in,
                              void* d_out, int out_size, void* d_ws, size_t ws_size,
                              hipStream_t stream) {
  const float* src = (const float*)d_in[0];
  const float* tgt = (const float*)d_in[1];
  float* ws = (float*)d_ws;
  float* out = (float*)d_out;
  hipMemsetAsync(d_ws, 0, 260 * sizeof(float), stream);  // zero accumulators + colsum
  rowstats_kernel<<<128, 256, 0, stream>>>(src, tgt, ws);
  bw_kernel<<<1, 256, 0, stream>>>(ws);
  cross_kernel<<<4096, 256, 0, stream>>>(src, tgt, ws);
  finalize_kernel<<<1, 1, 0, stream>>>(ws, out);
}

// Round 3
// 112.685 us; speedup vs baseline: 1.8639x; 1.8639x over previous
//
#include <hip/hip_runtime.h>
#include <hip/hip_bf16.h>

// MMD loss via bf16 MFMA Gram. ws layout (floats):
//  [0]   = S1 accumulator (sum of all row norms)
//  [1]   = cross-kernel sum accumulator
//  [2]   = c2 = -log2(e) / (16*bw)
//  [3]   = pad
//  [4..259]    = colsum[256]
//  [260..8451] = sqAll[8192] (row squared-norms, 0..4095 = source, 4096..8191 = target)

#define D 256
#define NROWS 4096

typedef __attribute__((ext_vector_type(8))) short short8;
typedef __attribute__((ext_vector_type(16))) float float16;

__device__ inline unsigned pack2_bf16(float a, float b) {
  // round-to-nearest-even fp32 -> bf16, two at a time, packed low|high
  unsigned ua = __float_as_uint(a);
  ua += 0x7FFFu + ((ua >> 16) & 1u);
  unsigned ub = __float_as_uint(b);
  ub += 0x7FFFu + ((ub >> 16) & 1u);
  return (ua >> 16) | (ub & 0xFFFF0000u);
}

__global__ __launch_bounds__(256) void rowstats_kernel(const float* __restrict__ src,
                                                       const float* __restrict__ tgt,
                                                       float* __restrict__ ws) {
  __shared__ float csL[4][256];
  __shared__ float s1L[4];
  int t = threadIdx.x;
  int wave = t >> 6, lane = t & 63;
  int rowBase = blockIdx.x * 64 + wave * 16;
  float cs0 = 0.f, cs1 = 0.f, cs2 = 0.f, cs3 = 0.f, s1 = 0.f;
  for (int r = 0; r < 16; ++r) {
    int row = rowBase + r;
    const float* p = (row < NROWS) ? (src + (size_t)row * D)
                                   : (tgt + (size_t)(row - NROWS) * D);
    float4 v = reinterpret_cast<const float4*>(p)[lane];
    cs0 += v.x; cs1 += v.y; cs2 += v.z; cs3 += v.w;
    float sq = v.x * v.x + v.y * v.y + v.z * v.z + v.w * v.w;
#pragma unroll
    for (int off = 32; off; off >>= 1) sq += __shfl_xor(sq, off, 64);
    if (lane == 0) { ws[260 + row] = sq; s1 += sq; }
  }
  csL[wave][lane * 4 + 0] = cs0;
  csL[wave][lane * 4 + 1] = cs1;
  csL[wave][lane * 4 + 2] = cs2;
  csL[wave][lane * 4 + 3] = cs3;
  if (lane == 0) s1L[wave] = s1;
  __syncthreads();
  float tot = csL[0][t] + csL[1][t] + csL[2][t] + csL[3][t];
  atomicAdd(&ws[4 + t], tot);
  if (t == 0) atomicAdd(&ws[0], s1L[0] + s1L[1] + s1L[2] + s1L[3]);
}

__global__ __launch_bounds__(256) void bw_kernel(float* __restrict__ ws) {
  __shared__ float red[256];
  int t = threadIdx.x;
  float c = ws[4 + t];
  red[t] = c * c;
  __syncthreads();
#pragma unroll
  for (int s = 128; s > 0; s >>= 1) {
    if (t < s) red[t] += red[t + s];
    __syncthreads();
  }
  if (t == 0) {
    double n = 8192.0;
    double sumL2 = 2.0 * n * (double)ws[0] - 2.0 * (double)red[0];
    double bw = sumL2 / (n * n - n) / 4.0;  // KERNEL_MUL^(KERNEL_NUM//2) = 4
    ws[2] = (float)(-1.4426950408889634 / (16.0 * bw));
  }
}

// Cross Gram block (4096x4096) via bf16 MFMA; fused multi-scale kernel epilogue.
// Tile 128x128, BK=64, 4 waves each owning 64x64 as 2x2 fragments of 32x32x16.
__global__ __launch_bounds__(256) void cross_kernel(const float* __restrict__ A,
                                                    const float* __restrict__ B,
                                                    float* __restrict__ ws) {
  __shared__ unsigned char Abuf[128 * 128];  // [row][64 bf16], 128B rows, XOR-swizzled
  __shared__ unsigned char Bbuf[128 * 128];
  __shared__ float sqAs[128], sqBs[128];
  __shared__ float red[256];
  int t = threadIdx.x;
  int bid = blockIdx.x;
  // XCD-aware 2D chunking: each XCD gets an 8x16 block rectangle (A 1MB + B 2MB fp32 -> fits 4MB L2)
  int xcd = bid & 7, q = bid >> 3;
  int bi = (xcd >> 1) * 8 + (q >> 4);
  int bj = (xcd & 1) * 16 + (q & 15);
  int rowBase = bi * 128, colBase = bj * 128;
  int wave = t >> 6, lane = t & 63;
  int wm = wave >> 1, wn = wave & 1;
  int hi = lane >> 5;
  int lr = lane & 31;
  int sr = t >> 4, sc = t & 15;

  if (t < 128) sqAs[t] = ws[260 + rowBase + t];
  else         sqBs[t - 128] = ws[260 + NROWS + colBase + (t - 128)];

  float16 acc00, acc01, acc10, acc11;
#pragma unroll
  for (int r = 0; r < 16; ++r) { acc00[r] = 0.f; acc01[r] = 0.f; acc10[r] = 0.f; acc11[r] = 0.f; }

  for (int k0 = 0; k0 < D; k0 += 64) {
#pragma unroll
    for (int i = 0; i < 8; ++i) {
      int r = sr + 16 * i;
      int swz = (sc * 8) ^ ((r & 7) << 4);
      float4 va = *reinterpret_cast<const float4*>(&A[(size_t)(rowBase + r) * D + k0 + sc * 4]);
      *reinterpret_cast<uint2*>(&Abuf[r * 128 + swz]) =
          make_uint2(pack2_bf16(va.x, va.y), pack2_bf16(va.z, va.w));
      float4 vb = *reinterpret_cast<const float4*>(&B[(size_t)(colBase + r) * D + k0 + sc * 4]);
      *reinterpret_cast<uint2*>(&Bbuf[r * 128 + swz]) =
          make_uint2(pack2_bf16(vb.x, vb.y), pack2_bf16(vb.z, vb.w));
    }
    __syncthreads();
#pragma unroll
    for (int ks = 0; ks < 4; ++ks) {
      int colb = ks * 32 + hi * 16;
      int ra0 = wm * 64 + lr;
      int ra1 = ra0 + 32;
      int rb0 = wn * 64 + lr;
      int rb1 = rb0 + 32;
      short8 a0 = *reinterpret_cast<const short8*>(&Abuf[ra0 * 128 + (colb ^ ((ra0 & 7) << 4))]);
      short8 a1 = *reinterpret_cast<const short8*>(&Abuf[ra1 * 128 + (colb ^ ((ra1 & 7) << 4))]);
      short8 b0 = *reinterpret_cast<const short8*>(&Bbuf[rb0 * 128 + (colb ^ ((rb0 & 7) << 4))]);
      short8 b1 = *reinterpret_cast<const short8*>(&Bbuf[rb1 * 128 + (colb ^ ((rb1 & 7) << 4))]);
      acc00 = __builtin_amdgcn_mfma_f32_32x32x16_bf16(a0, b0, acc00, 0, 0, 0);
      acc01 = __builtin_amdgcn_mfma_f32_32x32x16_bf16(a0, b1, acc01, 0, 0, 0);
      acc10 = __builtin_amdgcn_mfma_f32_32x32x16_bf16(a1, b0, acc10, 0, 0, 0);
      acc11 = __builtin_amdgcn_mfma_f32_32x32x16_bf16(a1, b1, acc11, 0, 0, 0);
    }
    __syncthreads();
  }

  // Epilogue: C/D layout col=lane&31, row=(reg&3)+8*(reg>>2)+4*(lane>>5)  [m74/m101]
  float c2 = ws[2];
  float local = 0.f;
#pragma unroll
  for (int m2 = 0; m2 < 2; ++m2) {
#pragma unroll
    for (int n2 = 0; n2 < 2; ++n2) {
      const float16& g = (m2 == 0) ? ((n2 == 0) ? acc00 : acc01)
                                   : ((n2 == 0) ? acc10 : acc11);
      float sB = sqBs[wn * 64 + n2 * 32 + lr];
#pragma unroll
      for (int r = 0; r < 16; ++r) {
        int row = (r & 3) + 8 * (r >> 2) + 4 * hi;
        float dd = sqAs[wm * 64 + m2 * 32 + row] + sB - 2.0f * g[r];
        float y = __builtin_amdgcn_exp2f(dd * c2);  // exp(-d/(16 bw))
        float y2 = y * y, y4 = y2 * y2, y8 = y4 * y4, y16 = y8 * y8;
        local += y + y2 + y4 + y8 + y16;
      }
    }
  }
  red[t] = local;
  __syncthreads();
#pragma unroll
  for (int s = 128; s > 0; s >>= 1) {
    if (t < s) red[t] += red[t + s];
    __syncthreads();
  }
  if (t == 0) atomicAdd(&ws[1], red[0]);
}

__global__ void finalize_kernel(const float* __restrict__ ws, float* __restrict__ out) {
  // mean over 4096*4096 cross block; loss = -XY - YX = -2*XY
  out[0] = -2.0f * (ws[1] * (1.0f / 16777216.0f));
}

extern "C" void kernel_launch(void* const* d_in, const int* in_sizes, int n_in,
                              void* d_out, int out_size, void* d_ws, size_t ws_size,
                              hipStream_t stream) {
  const float* src = (const float*)d_in[0];
  const float* tgt = (const float*)d_in[1];
  float* ws = (float*)d_ws;
  float* out = (float*)d_out;
  hipMemsetAsync(d_ws, 0, 260 * sizeof(float), stream);  // zero accumulators + colsum
  rowstats_kernel<<<128, 256, 0, stream>>>(src, tgt, ws);
  bw_kernel<<<1, 256, 0, stream>>>(ws);
  cross_kernel<<<1024, 256, 0, stream>>>(src, tgt, ws);
  finalize_kernel<<<1, 1, 0, stream>>>(ws, out);
}

// Round 4
// 94.788 us; speedup vs baseline: 2.2158x; 1.1888x over previous
//
#include <hip/hip_runtime.h>
#include <hip/hip_bf16.h>

// MMD loss, atomic-free reduction + bf16 MFMA Gram with global_load_lds staging.
//
// ws layout (float offsets):
//  [2]                 c2 = -log2(e)/(16*bw)
//  SQ_OFF   = 4        sq norms [8192] (0..4095 src, 4096..8191 tgt)
//  S1PART   = 8196     per-block sum-of-norms partials [128]
//  CROSSPART= 8324     per-block cross-kernel partials [1024]
//  COLPART  = 9348     per-block colsum partials [128][256]
//  ABF_OFF  = 42116    src as bf16 [4096*256] (= 524288 floats)  -- only if ws big enough
//  BBF_OFF  = 566404   tgt as bf16 [4096*256]
//  total    = 1090692 floats = 4362768 bytes

#define D 256
#define NROWS 4096
#define SQ_OFF 4
#define S1PART 8196
#define CROSSPART 8324
#define COLPART 9348
#define ABF_OFF 42116
#define BBF_OFF 566404
#define WS_NEED_FLOATS 1090692

typedef __attribute__((ext_vector_type(8))) short short8;
typedef __attribute__((ext_vector_type(16))) float float16;
typedef unsigned short ushort_t;

__device__ inline unsigned pack2_bf16(float a, float b) {
  // RNE fp32->bf16, two packed
  unsigned ua = __float_as_uint(a);
  ua += 0x7FFFu + ((ua >> 16) & 1u);
  unsigned ub = __float_as_uint(b);
  ub += 0x7FFFu + ((ub >> 16) & 1u);
  return (ua >> 16) | (ub & 0xFFFF0000u);
}

__device__ inline void gload_lds16(const ushort_t* g, ushort_t* l) {
  __builtin_amdgcn_global_load_lds(
      (const __attribute__((address_space(1))) unsigned int*)g,
      (__attribute__((address_space(3))) unsigned int*)l, 16, 0, 0);
}

// Prep: row norms, per-block colsum partial, per-block S1 partial, optional bf16 copies.
__global__ __launch_bounds__(256) void prep_kernel(const float* __restrict__ src,
                                                   const float* __restrict__ tgt,
                                                   float* __restrict__ ws,
                                                   int writeBf16) {
  __shared__ float csL[4][256];
  __shared__ float s1L[4];
  ushort_t* Abf = (ushort_t*)(ws + ABF_OFF);
  ushort_t* Bbf = (ushort_t*)(ws + BBF_OFF);
  int t = threadIdx.x;
  int wave = t >> 6, lane = t & 63;
  int rowBase = blockIdx.x * 64 + wave * 16;
  float cs0 = 0.f, cs1 = 0.f, cs2 = 0.f, cs3 = 0.f, s1 = 0.f;
  for (int r = 0; r < 16; ++r) {
    int row = rowBase + r;
    int isA = row < NROWS;
    const float* p = isA ? (src + (size_t)row * D) : (tgt + (size_t)(row - NROWS) * D);
    float4 v = reinterpret_cast<const float4*>(p)[lane];
    if (writeBf16) {
      ushort_t* dst = (isA ? Abf + (size_t)row * D : Bbf + (size_t)(row - NROWS) * D) + lane * 4;
      *reinterpret_cast<uint2*>(dst) = make_uint2(pack2_bf16(v.x, v.y), pack2_bf16(v.z, v.w));
    }
    cs0 += v.x; cs1 += v.y; cs2 += v.z; cs3 += v.w;
    float sq = v.x * v.x + v.y * v.y + v.z * v.z + v.w * v.w;
#pragma unroll
    for (int off = 32; off; off >>= 1) sq += __shfl_xor(sq, off, 64);
    if (lane == 0) { ws[SQ_OFF + row] = sq; s1 += sq; }
  }
  csL[wave][lane * 4 + 0] = cs0;
  csL[wave][lane * 4 + 1] = cs1;
  csL[wave][lane * 4 + 2] = cs2;
  csL[wave][lane * 4 + 3] = cs3;
  if (lane == 0) s1L[wave] = s1;
  __syncthreads();
  // plain stores, no atomics
  ws[COLPART + blockIdx.x * 256 + t] = csL[0][t] + csL[1][t] + csL[2][t] + csL[3][t];
  if (t == 0) ws[S1PART + blockIdx.x] = s1L[0] + s1L[1] + s1L[2] + s1L[3];
}

__global__ __launch_bounds__(256) void bw_kernel(float* __restrict__ ws) {
  __shared__ float red[256];
  __shared__ float s1red[128];
  int t = threadIdx.x;
  float colsum = 0.f;
#pragma unroll 8
  for (int b = 0; b < 128; ++b) colsum += ws[COLPART + b * 256 + t];
  red[t] = colsum * colsum;
  if (t < 128) s1red[t] = ws[S1PART + t];
  __syncthreads();
#pragma unroll
  for (int s = 128; s > 0; s >>= 1) {
    if (t < s) red[t] += red[t + s];
    if (s > 1 && t < (s >> 1)) s1red[t] += s1red[t + (s >> 1)];
    __syncthreads();
  }
  if (t == 0) {
    double n = 8192.0;
    double sumL2 = 2.0 * n * (double)s1red[0] - 2.0 * (double)red[0];
    double bw = sumL2 / (n * n - n) / 4.0;  // KERNEL_MUL^(KERNEL_NUM//2) = 4
    ws[2] = (float)(-1.4426950408889634 / (16.0 * bw));
  }
}

// Cross Gram (4096x4096) via bf16 MFMA; fused multi-scale kernel epilogue.
// Tile 128x128, BK=64, 4 waves each owning 64x64 as 2x2 frags of 32x32x16.
// LDS tiles [128 rows][64 bf16] with 16B-chunk XOR swizzle: chunk slot s of row r
// holds global chunk s ^ (r&7); read chunk c at slot c ^ (r&7).
template <int BF16SRC>
__global__ __launch_bounds__(256) void cross_kernel(const float* __restrict__ A32,
                                                    const float* __restrict__ B32,
                                                    const ushort_t* __restrict__ Abf,
                                                    const ushort_t* __restrict__ Bbf,
                                                    float* __restrict__ ws) {
  __shared__ ushort_t Abuf[128 * 64];  // 16 KB
  __shared__ ushort_t Bbuf[128 * 64];
  __shared__ float sqAs[128], sqBs[128];
  __shared__ float red[256];
  int t = threadIdx.x;
  int bid = blockIdx.x;
  // XCD-aware 2D chunking: each XCD gets an 8x16 rectangle of 128^2 tiles
  int xcd = bid & 7, q = bid >> 3;
  int bi = (xcd >> 1) * 8 + (q >> 4);
  int bj = (xcd & 1) * 16 + (q & 15);
  int rowBase = bi * 128, colBase = bj * 128;
  int wave = t >> 6, lane = t & 63;
  int wm = wave >> 1, wn = wave & 1;
  int hi = lane >> 5;
  int lr = lane & 31;
  int sr = t >> 4, sc = t & 15;  // fallback staging coords

  if (t < 128) sqAs[t] = ws[SQ_OFF + rowBase + t];
  else         sqBs[t - 128] = ws[SQ_OFF + NROWS + colBase + (t - 128)];

  float16 acc00, acc01, acc10, acc11;
#pragma unroll
  for (int r = 0; r < 16; ++r) { acc00[r] = 0.f; acc01[r] = 0.f; acc10[r] = 0.f; acc11[r] = 0.f; }

  // per-lane source chunk permutation for swizzled global_load_lds staging
  int lrow8 = lane >> 3;                      // row within 8-row group
  int lchunk = (lane & 7) ^ lrow8;            // inverse-swizzled global 16B chunk
  for (int k0 = 0; k0 < D; k0 += 64) {
    if (BF16SRC) {
      int w32 = wave * 32;
#pragma unroll
      for (int j = 0; j < 4; ++j) {
        int r0 = w32 + j * 8;
        gload_lds16(Abf + (size_t)(rowBase + r0 + lrow8) * D + k0 + (lchunk << 3),
                    &Abuf[r0 * 64]);
        gload_lds16(Bbf + (size_t)(colBase + r0 + lrow8) * D + k0 + (lchunk << 3),
                    &Bbuf[r0 * 64]);
      }
    } else {
#pragma unroll
      for (int i = 0; i < 8; ++i) {
        int r = sr + 16 * i;
        int swz = (sc * 4) ^ ((r & 7) << 3);  // ushort units
        float4 va = *reinterpret_cast<const float4*>(&A32[(size_t)(rowBase + r) * D + k0 + sc * 4]);
        *reinterpret_cast<uint2*>(&Abuf[r * 64 + swz]) =
            make_uint2(pack2_bf16(va.x, va.y), pack2_bf16(va.z, va.w));
        float4 vb = *reinterpret_cast<const float4*>(&B32[(size_t)(colBase + r) * D + k0 + sc * 4]);
        *reinterpret_cast<uint2*>(&Bbuf[r * 64 + swz]) =
            make_uint2(pack2_bf16(vb.x, vb.y), pack2_bf16(vb.z, vb.w));
      }
    }
    __syncthreads();  // drains vmcnt (global_load_lds) + lgkm
#pragma unroll
    for (int ks = 0; ks < 4; ++ks) {
      int c0 = ks * 2 + hi;  // 16B chunk index within 128B row
      int ra0 = wm * 64 + lr, ra1 = ra0 + 32;
      int rb0 = wn * 64 + lr, rb1 = rb0 + 32;
      short8 a0 = *reinterpret_cast<const short8*>(&Abuf[ra0 * 64 + ((c0 ^ (ra0 & 7)) << 3)]);
      short8 a1 = *reinterpret_cast<const short8*>(&Abuf[ra1 * 64 + ((c0 ^ (ra1 & 7)) << 3)]);
      short8 b0 = *reinterpret_cast<const short8*>(&Bbuf[rb0 * 64 + ((c0 ^ (rb0 & 7)) << 3)]);
      short8 b1 = *reinterpret_cast<const short8*>(&Bbuf[rb1 * 64 + ((c0 ^ (rb1 & 7)) << 3)]);
      acc00 = __builtin_amdgcn_mfma_f32_32x32x16_bf16(a0, b0, acc00, 0, 0, 0);
      acc01 = __builtin_amdgcn_mfma_f32_32x32x16_bf16(a0, b1, acc01, 0, 0, 0);
      acc10 = __builtin_amdgcn_mfma_f32_32x32x16_bf16(a1, b0, acc10, 0, 0, 0);
      acc11 = __builtin_amdgcn_mfma_f32_32x32x16_bf16(a1, b1, acc11, 0, 0, 0);
    }
    __syncthreads();
  }

  // Epilogue: C/D layout col=lane&31, row=(reg&3)+8*(reg>>2)+4*(lane>>5)  [m74/m101]
  float c2 = ws[2];
  float local = 0.f;
#pragma unroll
  for (int m2 = 0; m2 < 2; ++m2) {
#pragma unroll
    for (int n2 = 0; n2 < 2; ++n2) {
      const float16& g = (m2 == 0) ? ((n2 == 0) ? acc00 : acc01)
                                   : ((n2 == 0) ? acc10 : acc11);
      float sB = sqBs[wn * 64 + n2 * 32 + lr];
#pragma unroll
      for (int r = 0; r < 16; ++r) {
        int row = (r & 3) + 8 * (r >> 2) + 4 * hi;
        float dd = sqAs[wm * 64 + m2 * 32 + row] + sB - 2.0f * g[r];
        float y = __builtin_amdgcn_exp2f(dd * c2);  // exp(-d/(16 bw))
        float y2 = y * y, y4 = y2 * y2, y8 = y4 * y4, y16 = y8 * y8;
        local += y + y2 + y4 + y8 + y16;
      }
    }
  }
  red[t] = local;
  __syncthreads();
#pragma unroll
  for (int s = 128; s > 0; s >>= 1) {
    if (t < s) red[t] += red[t + s];
    __syncthreads();
  }
  if (t == 0) ws[CROSSPART + bid] = red[0];  // plain store, no atomic
}

__global__ __launch_bounds__(256) void finalize_kernel(const float* __restrict__ ws,
                                                       float* __restrict__ out) {
  __shared__ float red[256];
  int t = threadIdx.x;
  red[t] = ws[CROSSPART + t] + ws[CROSSPART + 256 + t] +
           ws[CROSSPART + 512 + t] + ws[CROSSPART + 768 + t];
  __syncthreads();
#pragma unroll
  for (int s = 128; s > 0; s >>= 1) {
    if (t < s) red[t] += red[t + s];
    __syncthreads();
  }
  if (t == 0) out[0] = -2.0f * (red[0] * (1.0f / 16777216.0f));
}

extern "C" void kernel_launch(void* const* d_in, const int* in_sizes, int n_in,
                              void* d_out, int out_size, void* d_ws, size_t ws_size,
                              hipStream_t stream) {
  const float* src = (const float*)d_in[0];
  const float* tgt = (const float*)d_in[1];
  float* ws = (float*)d_ws;
  float* out = (float*)d_out;
  int useBf16 = ws_size >= (size_t)WS_NEED_FLOATS * sizeof(float);
  const ushort_t* Abf = (const ushort_t*)(ws + ABF_OFF);
  const ushort_t* Bbf = (const ushort_t*)(ws + BBF_OFF);

  prep_kernel<<<128, 256, 0, stream>>>(src, tgt, ws, useBf16);
  bw_kernel<<<1, 256, 0, stream>>>(ws);
  if (useBf16)
    cross_kernel<1><<<1024, 256, 0, stream>>>(src, tgt, Abf, Bbf, ws);
  else
    cross_kernel<0><<<1024, 256, 0, stream>>>(src, tgt, Abf, Bbf, ws);
  finalize_kernel<<<1, 256, 0, stream>>>(ws, out);
}